// Round 15
// baseline (3479.179 us; speedup 1.0000x reference)
//
#include <hip/hip_runtime.h>

#define T_DIM 512
#define B_DIM 64
#define F_DIM 128
#define H_DIM 512
#define CHS 64   // chunk steps (R15: 32 -> 64, halves launch count)
#define NCH 8    // chunks per layer

typedef _Float16 f16x8 __attribute__((ext_vector_type(8)));
typedef _Float16 f16x4 __attribute__((ext_vector_type(4)));
typedef float f32x4 __attribute__((ext_vector_type(4)));

// ---------------------------------------------------------------------------
// prep: dst[j][k] f16 = src[k][j]
// ---------------------------------------------------------------------------
__global__ void prepT(_Float16* __restrict__ dst, const float* __restrict__ src) {
  int idx = blockIdx.x * blockDim.x + threadIdx.x;
  if (idx < 262144) {
    int j = idx >> 9, k = idx & 511;
    dst[idx] = (_Float16)src[k * 512 + j];
  }
}

// ---------------------------------------------------------------------------
// prep: wcat[l][n=512][kc=640]: l0 [wi0|ws0]; l1 ws1; l2 ws2
// ---------------------------------------------------------------------------
__global__ void prep_wcat2(_Float16* __restrict__ dst, const float* __restrict__ wi0,
                           const float* __restrict__ ws0, const float* __restrict__ ws1,
                           const float* __restrict__ ws2) {
  const long total = 3L * 512 * 640;
  for (long idx = (long)blockIdx.x * blockDim.x + threadIdx.x; idx < total;
       idx += (long)gridDim.x * blockDim.x) {
    int l = (int)(idx / 327680);
    int rem = (int)(idx % 327680);
    int n = rem / 640, kc = rem % 640;
    float v = 0.f;
    if (l == 0) {
      if (kc < 128) v = wi0[kc * 512 + n];
      else if (kc < 256) v = ws0[(kc - 128) * 512 + n];
    } else {
      const float* ws = (l == 1) ? ws1 : ws2;
      if (kc < 128) v = ws[kc * 512 + n];
    }
    dst[idx] = (_Float16)v;
  }
}

// ---------------------------------------------------------------------------
// build A' panel f16 (verified; inK=0 -> sxs-only width-128 panel)
// ---------------------------------------------------------------------------
__global__ void build_A(_Float16* __restrict__ Abuf, const float* __restrict__ xin,
                        const float* __restrict__ prev, int n, int inK, int scale,
                        int layer) {
  const int Kcat = inK + 128;
  const long total = (long)n * 64 * Kcat;
  for (long idx = (long)blockIdx.x * blockDim.x + threadIdx.x; idx < total;
       idx += (long)gridDim.x * blockDim.x) {
    int k = (int)(idx % Kcat);
    long r = idx / Kcat;
    int b = (int)(r & 63);
    int t = (int)(r >> 6);
    float v;
    if (k < inK) {
      if (layer == 0) v = xin[((long)b * T_DIM + t) * F_DIM + k];
      else v = prev[((long)(t + scale - 1) * B_DIM + b) * H_DIM + k];
    } else {
      int kk = k - inK;
      int t0 = t + scale - 1;
      float s = 0.f;
      for (int w = 0; w < scale; ++w) s += xin[((long)b * T_DIM + t0 + w) * F_DIM + kk];
      v = s * (1.f / scale);
    }
    Abuf[idx] = (_Float16)v;
  }
}

// ---------------------------------------------------------------------------
// f16 MFMA GEMM (prologue, verified; B stride 640)
// ---------------------------------------------------------------------------
__global__ __launch_bounds__(256) void gemm_f16(const _Float16* __restrict__ A,
                                                const _Float16* __restrict__ Bt,
                                                float* __restrict__ C, int Mrows,
                                                int Kcat) {
  __shared__ _Float16 As[128][72];
  __shared__ _Float16 Bs[128][72];
  const int tid = threadIdx.x;
  const int tn = blockIdx.x, tm = blockIdx.y;
  const int lane = tid & 63, wid = tid >> 6;
  const int wm = wid >> 1, wn = wid & 1;
  f32x4 acc[4][4] = {};
  const int nK = Kcat >> 6;
  const int lrow = tid >> 3, lkc = (tid & 7) * 8;

  for (int kt = 0; kt < nK; ++kt) {
    for (int r = 0; r < 4; ++r) {
      int row = r * 32 + lrow;
      int grow = tm * 128 + row;
      uint4 va = make_uint4(0u, 0u, 0u, 0u);
      if (grow < Mrows) va = *(const uint4*)&A[(size_t)grow * Kcat + kt * 64 + lkc];
      *(uint4*)&As[row][lkc] = va;
      uint4 vb = *(const uint4*)&Bt[(size_t)(tn * 128 + row) * 640 + kt * 64 + lkc];
      *(uint4*)&Bs[row][lkc] = vb;
    }
    __syncthreads();
#pragma unroll
    for (int kk = 0; kk < 64; kk += 32) {
      f16x8 af[4], bf[4];
#pragma unroll
      for (int mt = 0; mt < 4; ++mt)
        af[mt] = *(const f16x8*)&As[wm * 64 + mt * 16 + (lane & 15)][kk + (lane >> 4) * 8];
#pragma unroll
      for (int nt = 0; nt < 4; ++nt)
        bf[nt] = *(const f16x8*)&Bs[wn * 64 + nt * 16 + (lane & 15)][kk + (lane >> 4) * 8];
#pragma unroll
      for (int mt = 0; mt < 4; ++mt)
#pragma unroll
        for (int nt = 0; nt < 4; ++nt)
          acc[mt][nt] = __builtin_amdgcn_mfma_f32_16x16x32_f16(af[mt], bf[nt], acc[mt][nt], 0, 0, 0);
    }
    __syncthreads();
  }

  const int crow0 = tm * 128 + wm * 64 + (lane >> 4) * 4;
  const int ccol0 = tn * 128 + wn * 64 + (lane & 15);
#pragma unroll
  for (int mt = 0; mt < 4; ++mt)
#pragma unroll
    for (int q = 0; q < 4; ++q) {
      int grow = crow0 + mt * 16 + q;
      if (grow < Mrows) {
#pragma unroll
        for (int nt = 0; nt < 4; ++nt)
          C[(size_t)grow * 512 + ccol0 + nt * 16] = acc[mt][nt][q];
      }
    }
}

// ---------------------------------------------------------------------------
// pipe_step (R14 structure, CHS=64): XCD-partitioned roles. grid=128.
//   xcd 0..2, slot<4 : rec layer=xcd, group=slot
//   xcd 4,5          : gemm1 (tm=slot, tn=xcd-4)
//   xcd 6,7          : gemm2 (tm=slot, tn=xcd-6)
// Stream order carries all cross-stage deps; no spins/fences/atomics.
// ---------------------------------------------------------------------------
__global__ __launch_bounds__(512, 2) void pipe_step(
    float* __restrict__ out0, float* __restrict__ out1, float* __restrict__ out2,
    const _Float16* __restrict__ whT16, const _Float16* __restrict__ wiT16,
    int ca, int cb, int cc, int cd, int ce) {
  __shared__ char ldsRaw[163840];
  const int blk = blockIdx.x;
  const int xcd = blk & 7;
  const int slot = blk >> 3;
  const int tid = threadIdx.x;
  const int lane = tid & 63, wid = tid >> 6;
  const int nL[3] = {511, 509, 505};

  if (xcd < 3) {
    // ------------------------------ REC role ------------------------------
    if (slot >= 4) return;
    const int l = xcd;
    const int gg = slot;
    const int chunk = (l == 0) ? ca : (l == 1) ? cb : cc;
    if (chunk < 0 || chunk >= NCH) return;
    const int n = nL[l];
    const int s0 = chunk * CHS;
    if (s0 >= n) return;
    const int ns = (s0 + CHS < n) ? CHS : (n - s0);
    float* po = (l == 0) ? out0 : (l == 1) ? out1 : out2;
    const _Float16* whT = whT16 + (size_t)l * 262144;

    _Float16* hstage = (_Float16*)ldsRaw;            // 2 x 8192 f16 = 32 KB
    _Float16* Blds = (_Float16*)(ldsRaw + 32768);    // 128 KB, kb 10..13

    const int colbase = wid * 64;
    const int bq = lane & 15;
    const int u = lane >> 4;
    const int gnb = wid * 4;

    // Blds fill (kb 10..13, frag order)
    {
      uint4* B4 = (uint4*)Blds;
      for (int p = 0; p < 16; ++p) {
        int flat = p * 512 + tid;
        int ll = flat & 63;
        int gn = (flat >> 6) & 31;
        int kbl = flat >> 11;
        B4[flat] = *(const uint4*)&whT[(size_t)(gn * 16 + (ll & 15)) * 512 +
                                       (kbl + 10) * 32 + (ll >> 4) * 8];
      }
    }
    // kb 0..9 -> registers, residency forced (R8-verified)
    f16x8 bfr[4][10];
    {
#pragma unroll
      for (int nt = 0; nt < 4; ++nt) {
        const int j = colbase + nt * 16 + bq;
#pragma unroll
        for (int kb = 0; kb < 10; ++kb)
          bfr[nt][kb] = *(const f16x8*)&whT[(size_t)j * 512 + kb * 32 + u * 8];
      }
#pragma unroll
      for (int nt = 0; nt < 4; ++nt)
#pragma unroll
        for (int kb = 0; kb < 10; ++kb) asm volatile("" : "+v"(bfr[nt][kb]));
    }
    // chunk-start: re-stage h_{s0-1} from f32 out into hstage slot map
    if (s0 > 0) {
      _Float16* hw0 = hstage + ((s0 - 1) & 1) * 8192;
      for (int rep = 0; rep < 2; ++rep) {
        int idx = rep * 512 + tid;          // 0..1023
        int lb = idx >> 6;                  // 0..15
        int j0 = (idx & 63) * 8;
        const float* s = po + (size_t)(s0 - 1) * 32768 + (size_t)(gg * 16 + lb) * 512 + j0;
        float4 x0 = *(const float4*)s;
        float4 x1 = *(const float4*)(s + 4);
        f16x8 hv;
        hv[0] = (_Float16)x0.x; hv[1] = (_Float16)x0.y;
        hv[2] = (_Float16)x0.z; hv[3] = (_Float16)x0.w;
        hv[4] = (_Float16)x1.x; hv[5] = (_Float16)x1.y;
        hv[6] = (_Float16)x1.z; hv[7] = (_Float16)x1.w;
        int slot2 = (j0 >> 5) * 64 + ((j0 >> 3) & 3) * 16 + (lb ^ ((j0 >> 3) & 1));
        *(f16x8*)&hw0[slot2 * 8] = hv;
      }
    }
    __syncthreads();

    const int b0g = gg * 16;
    const size_t base = (size_t)(b0g + bq) * 512 + colbase + u * 4;

#define AFRD(kb) (*(const f16x8*)&hs[((kb)*64 + u * 16 + (bq ^ (u & 1))) * 8])
#define BLRD(kb, nt) \
  (*(const f16x8*)&Blds[((((kb)-10) * 32 + gnb + (nt)) * 64 + lane) * 8])
#define GLOAD(kb, nt) \
  (*(const f16x8*)&whT[(size_t)(colbase + (nt)*16 + bq) * 512 + (kb)*32 + u * 8])

    for (int t = s0; t < s0 + ns; ++t) {
      const float* pc = po + (size_t)t * 32768 + base;
      f32x4 pre[4];
#pragma unroll
      for (int nt = 0; nt < 4; ++nt) pre[nt] = *(const f32x4*)&pc[nt * 16];

      f32x4 acc[4] = {};
      if (t > 0) {
        const _Float16* hs = hstage + ((t - 1) & 1) * 8192;
        constexpr int seq[16] = {10, 0, 1, 2, 3, 11, 4, 5, 14, 12, 6, 7, 13, 8, 9, 15};
        constexpr int lnx[16] = {11, -1, -1, -1, -1, 12, -1, -1, -1, 13, -1, -1, -1, -1, -1, -1};
        f16x8 afr[4];
#pragma unroll
        for (int i = 0; i < 4; ++i) afr[i] = AFRD(seq[i]);
        f16x8 blr[4];
#pragma unroll
        for (int nt = 0; nt < 4; ++nt) blr[nt] = BLRD(10, nt);
        f16x8 gfr[4];
#pragma unroll
        for (int nt = 0; nt < 4; ++nt) gfr[nt] = GLOAD(14, nt);

#pragma unroll
        for (int i = 0; i < 16; ++i) {
          const int kb = seq[i];
          f16x8 a = afr[i & 3];
          if (i + 4 < 16) afr[i & 3] = AFRD(seq[i + 4]);
          if (kb < 10) {
#pragma unroll
            for (int nt = 0; nt < 4; ++nt)
              acc[nt] = __builtin_amdgcn_mfma_f32_16x16x32_f16(bfr[nt][kb], a, acc[nt], 0, 0, 0);
          } else if (kb < 14) {
            f16x8 w[4];
#pragma unroll
            for (int nt = 0; nt < 4; ++nt) w[nt] = blr[nt];
            if (lnx[i] >= 0) {
#pragma unroll
              for (int nt = 0; nt < 4; ++nt) blr[nt] = BLRD(lnx[i], nt);
            }
#pragma unroll
            for (int nt = 0; nt < 4; ++nt)
              acc[nt] = __builtin_amdgcn_mfma_f32_16x16x32_f16(w[nt], a, acc[nt], 0, 0, 0);
          } else if (kb == 14) {
            f16x8 w[4];
#pragma unroll
            for (int nt = 0; nt < 4; ++nt) w[nt] = gfr[nt];
#pragma unroll
            for (int nt = 0; nt < 4; ++nt) gfr[nt] = GLOAD(15, nt);
#pragma unroll
            for (int nt = 0; nt < 4; ++nt)
              acc[nt] = __builtin_amdgcn_mfma_f32_16x16x32_f16(w[nt], a, acc[nt], 0, 0, 0);
          } else {
#pragma unroll
            for (int nt = 0; nt < 4; ++nt)
              acc[nt] = __builtin_amdgcn_mfma_f32_16x16x32_f16(gfr[nt], a, acc[nt], 0, 0, 0);
          }
        }
      }

      _Float16* hw = hstage + (t & 1) * 8192;
      float* pw = po + (size_t)t * 32768 + base;
#pragma unroll
      for (int nt = 0; nt < 4; ++nt) {
        const int J = colbase + nt * 16 + u * 4;
        const int slot2 = (J >> 5) * 64 + ((J >> 3) & 3) * 16 + (bq ^ ((J >> 3) & 1));
        f16x4 h4;
#pragma unroll
        for (int q = 0; q < 4; ++q) {
          float a = acc[nt][q] + pre[nt][q];
          float e = __builtin_amdgcn_exp2f(a * 2.8853900817779268f);
          float h = 1.f - 2.f * __builtin_amdgcn_rcpf(e + 1.f);
          acc[nt][q] = h;
          h4[q] = (_Float16)h;
        }
        *(f16x4*)&hw[slot2 * 8 + (J & 7)] = h4;
        *(f32x4*)&pw[nt * 16] = acc[nt];
      }
      asm volatile("s_waitcnt lgkmcnt(0)\n\ts_barrier" ::: "memory");
    }
#undef AFRD
#undef BLRD
#undef GLOAD
  } else if (xcd >= 4) {
    // ------------------------------ GEMM role ------------------------------
    // out_l[t][b][:] += h_{l-1}[t+toff][b][:] @ wi_l   (C-add; launch-ordered)
    const int which = (xcd - 4) >> 1;  // 0: gemm1 (xcd 4,5), 1: gemm2 (xcd 6,7)
    const int chunk = which ? ce : cd;
    if (chunk < 0 || chunk >= NCH) return;
    const int l = which + 1;
    const int n = nL[l];
    const int t0 = chunk * CHS;
    if (t0 >= n) return;
    const int t1 = (t0 + CHS < n) ? (t0 + CHS) : n;
    const int Mrows = (t1 - t0) * 64;
    const int Mbase = t0 * 64;
    const int toff = which ? 3 : 1;
    const float* hsrc = which ? out1 : out0;
    float* C = which ? out2 : out1;
    const _Float16* Bt = wiT16 + (size_t)which * 262144;  // [n=512][k=512]

    // CHS=64 -> chunk has up to 4096 rows = 32 Mtiles of 128; 16 slots x 2
    // passes each. tn from xcd parity as before.
    const int tn = (xcd - 4) & 1;   // 0..1  (2 Ntiles of 256 cols)
    _Float16(*As)[72] = (_Float16(*)[72])ldsRaw;                    // 128x72
    _Float16(*Bs)[72] = (_Float16(*)[72])(ldsRaw + 128 * 72 * 2);   // 256x72
    const int wm = wid >> 2, wn = wid & 3;
    const int nMt = (Mrows + 127) >> 7;

    for (int tm = slot; tm < nMt; tm += 16) {
      f32x4 acc[4][4] = {};

      for (int kt = 0; kt < 8; ++kt) {
        // A: 128 rows x 64 k (f32 source -> f16), 1024 8-f16 pieces, 2/thread
        for (int rep = 0; rep < 2; ++rep) {
          int idx = rep * 512 + tid;
          int row = idx >> 3;
          int kc8 = (idx & 7) * 8;
          f16x8 hv = {};
          if (tm * 128 + row < Mrows) {
            int grow = Mbase + tm * 128 + row;
            int tt = grow >> 6, bb = grow & 63;
            const float* s = hsrc + (size_t)(tt + toff) * 32768 + (size_t)bb * 512 + kt * 64 + kc8;
            float4 x0 = *(const float4*)s;
            float4 x1 = *(const float4*)(s + 4);
            hv[0] = (_Float16)x0.x; hv[1] = (_Float16)x0.y;
            hv[2] = (_Float16)x0.z; hv[3] = (_Float16)x0.w;
            hv[4] = (_Float16)x1.x; hv[5] = (_Float16)x1.y;
            hv[6] = (_Float16)x1.z; hv[7] = (_Float16)x1.w;
          }
          *(f16x8*)&As[row][kc8] = hv;
        }
        // B: 256 rows x 64 k f16, 2048 pieces, 4/thread
        for (int rep = 0; rep < 4; ++rep) {
          int idx = rep * 512 + tid;
          int row = idx >> 3;
          int kc8 = (idx & 7) * 8;
          *(uint4*)&Bs[row][kc8] =
              *(const uint4*)&Bt[(size_t)(tn * 256 + row) * 512 + kt * 64 + kc8];
        }
        __syncthreads();
#pragma unroll
        for (int kk = 0; kk < 64; kk += 32) {
          f16x8 af[4], bf[4];
#pragma unroll
          for (int mt = 0; mt < 4; ++mt)
            af[mt] = *(const f16x8*)&As[wm * 64 + mt * 16 + (lane & 15)][kk + (lane >> 4) * 8];
#pragma unroll
          for (int nt = 0; nt < 4; ++nt)
            bf[nt] = *(const f16x8*)&Bs[wn * 64 + nt * 16 + (lane & 15)][kk + (lane >> 4) * 8];
#pragma unroll
          for (int mt = 0; mt < 4; ++mt)
#pragma unroll
            for (int nt = 0; nt < 4; ++nt)
              acc[mt][nt] = __builtin_amdgcn_mfma_f32_16x16x32_f16(af[mt], bf[nt], acc[mt][nt], 0, 0, 0);
        }
        __syncthreads();
      }

      const int crow0 = tm * 128 + wm * 64 + (lane >> 4) * 4;
      const int ccol0 = tn * 256 + wn * 64 + (lane & 15);
#pragma unroll
      for (int mt = 0; mt < 4; ++mt)
#pragma unroll
        for (int q = 0; q < 4; ++q) {
          int lrow = crow0 + mt * 16 + q;
          if (lrow < Mrows) {
            size_t grow = (size_t)(Mbase + lrow);
#pragma unroll
            for (int nt = 0; nt < 4; ++nt)
              C[grow * 512 + ccol0 + nt * 16] += acc[mt][nt][q];
          }
        }
      __syncthreads();
    }
  }
}

// ---------------------------------------------------------------------------
extern "C" void kernel_launch(void* const* d_in, const int* in_sizes, int n_in,
                              void* d_out, int out_size, void* d_ws, size_t ws_size,
                              hipStream_t stream) {
  const float* inputs = (const float*)d_in[0];
  const float* wi[3] = {(const float*)d_in[1], (const float*)d_in[4], (const float*)d_in[7]};
  const float* wsm[3] = {(const float*)d_in[2], (const float*)d_in[5], (const float*)d_in[8]};
  const float* wh[3] = {(const float*)d_in[3], (const float*)d_in[6], (const float*)d_in[9]};
  float* out = (float*)d_out;

  char* wsp = (char*)d_ws;
  _Float16* whT16 = (_Float16*)wsp;                   // 1,572,864
  _Float16* wiT16 = (_Float16*)(wsp + 1572864);       // 1,048,576
  _Float16* wcat = (_Float16*)(wsp + 2621440);        // 1,966,080
  _Float16* Abuf = (_Float16*)(wsp + 4587520);        // prologue only

  for (int l = 0; l < 3; ++l)
    prepT<<<1024, 256, 0, stream>>>(whT16 + (size_t)l * 262144, wh[l]);
  prepT<<<1024, 256, 0, stream>>>(wiT16, wi[1]);
  prepT<<<1024, 256, 0, stream>>>(wiT16 + 262144, wi[2]);
  prep_wcat2<<<1024, 256, 0, stream>>>(wcat, wi[0], wsm[0], wsm[1], wsm[2]);

  const int nL[3] = {511, 509, 505};
  const long offL[3] = {0L, 511L * 32768, (511L + 509L) * 32768};
  float* out0 = out;
  float* out1 = out + offL[1];
  float* out2 = out + offL[2];

  // prologue: layer0 full pre; layer1/2 preS (ws terms)
  build_A<<<4096, 256, 0, stream>>>(Abuf, inputs, nullptr, nL[0], 128, 1, 0);
  gemm_f16<<<dim3(4, (nL[0] * 64 + 127) / 128), 256, 0, stream>>>(
      Abuf, wcat, out0, nL[0] * 64, 256);
  build_A<<<2048, 256, 0, stream>>>(Abuf, inputs, nullptr, nL[1], 0, 2, 1);
  gemm_f16<<<dim3(4, (nL[1] * 64 + 127) / 128), 256, 0, stream>>>(
      Abuf, wcat + 512 * 640, out1, nL[1] * 64, 128);
  build_A<<<2048, 256, 0, stream>>>(Abuf, inputs, nullptr, nL[2], 0, 4, 1);
  gemm_f16<<<dim3(4, (nL[2] * 64 + 127) / 128), 256, 0, stream>>>(
      Abuf, wcat + 2 * 512 * 640, out2, nL[2] * 64, 128);

  // chunked pipeline: launch i runs rec0[i] | gemm1[i-2] | rec1[i-3]
  //                   | gemm2[i-5] | rec2[i-6]; stream order = dependencies.
  for (int i = 0; i <= NCH + 5; ++i)
    pipe_step<<<128, 512, 0, stream>>>(out0, out1, out2, whT16, wiT16,
                                       i, i - 3, i - 6, i - 2, i - 5);
}

// Round 16
// 2980.404 us; speedup vs baseline: 1.1674x; 1.1674x over previous
//
#include <hip/hip_runtime.h>

#define T_DIM 512
#define B_DIM 64
#define F_DIM 128
#define H_DIM 512
#define CHS 32   // chunk steps (R13 proven)
#define NCH 16   // chunks per layer

typedef _Float16 f16x8 __attribute__((ext_vector_type(8)));
typedef _Float16 f16x4 __attribute__((ext_vector_type(4)));
typedef float f32x4 __attribute__((ext_vector_type(4)));

// ---------------------------------------------------------------------------
// prep: dst[j][k] f16 = src[k][j]
// ---------------------------------------------------------------------------
__global__ void prepT(_Float16* __restrict__ dst, const float* __restrict__ src) {
  int idx = blockIdx.x * blockDim.x + threadIdx.x;
  if (idx < 262144) {
    int j = idx >> 9, k = idx & 511;
    dst[idx] = (_Float16)src[k * 512 + j];
  }
}

// ---------------------------------------------------------------------------
// prep: wcat[l][n=512][kc=640]: l0 [wi0|ws0]; l1 ws1; l2 ws2
// ---------------------------------------------------------------------------
__global__ void prep_wcat2(_Float16* __restrict__ dst, const float* __restrict__ wi0,
                           const float* __restrict__ ws0, const float* __restrict__ ws1,
                           const float* __restrict__ ws2) {
  const long total = 3L * 512 * 640;
  for (long idx = (long)blockIdx.x * blockDim.x + threadIdx.x; idx < total;
       idx += (long)gridDim.x * blockDim.x) {
    int l = (int)(idx / 327680);
    int rem = (int)(idx % 327680);
    int n = rem / 640, kc = rem % 640;
    float v = 0.f;
    if (l == 0) {
      if (kc < 128) v = wi0[kc * 512 + n];
      else if (kc < 256) v = ws0[(kc - 128) * 512 + n];
    } else {
      const float* ws = (l == 1) ? ws1 : ws2;
      if (kc < 128) v = ws[kc * 512 + n];
    }
    dst[idx] = (_Float16)v;
  }
}

// ---------------------------------------------------------------------------
// build A' panel f16 (verified; inK=0 -> sxs-only width-128 panel)
// ---------------------------------------------------------------------------
__global__ void build_A(_Float16* __restrict__ Abuf, const float* __restrict__ xin,
                        const float* __restrict__ prev, int n, int inK, int scale,
                        int layer) {
  const int Kcat = inK + 128;
  const long total = (long)n * 64 * Kcat;
  for (long idx = (long)blockIdx.x * blockDim.x + threadIdx.x; idx < total;
       idx += (long)gridDim.x * blockDim.x) {
    int k = (int)(idx % Kcat);
    long r = idx / Kcat;
    int b = (int)(r & 63);
    int t = (int)(r >> 6);
    float v;
    if (k < inK) {
      if (layer == 0) v = xin[((long)b * T_DIM + t) * F_DIM + k];
      else v = prev[((long)(t + scale - 1) * B_DIM + b) * H_DIM + k];
    } else {
      int kk = k - inK;
      int t0 = t + scale - 1;
      float s = 0.f;
      for (int w = 0; w < scale; ++w) s += xin[((long)b * T_DIM + t0 + w) * F_DIM + kk];
      v = s * (1.f / scale);
    }
    Abuf[idx] = (_Float16)v;
  }
}

// ---------------------------------------------------------------------------
// f16 MFMA GEMM (prologue, verified; B stride 640)
// ---------------------------------------------------------------------------
__global__ __launch_bounds__(256) void gemm_f16(const _Float16* __restrict__ A,
                                                const _Float16* __restrict__ Bt,
                                                float* __restrict__ C, int Mrows,
                                                int Kcat) {
  __shared__ _Float16 As[128][72];
  __shared__ _Float16 Bs[128][72];
  const int tid = threadIdx.x;
  const int tn = blockIdx.x, tm = blockIdx.y;
  const int lane = tid & 63, wid = tid >> 6;
  const int wm = wid >> 1, wn = wid & 1;
  f32x4 acc[4][4] = {};
  const int nK = Kcat >> 6;
  const int lrow = tid >> 3, lkc = (tid & 7) * 8;

  for (int kt = 0; kt < nK; ++kt) {
    for (int r = 0; r < 4; ++r) {
      int row = r * 32 + lrow;
      int grow = tm * 128 + row;
      uint4 va = make_uint4(0u, 0u, 0u, 0u);
      if (grow < Mrows) va = *(const uint4*)&A[(size_t)grow * Kcat + kt * 64 + lkc];
      *(uint4*)&As[row][lkc] = va;
      uint4 vb = *(const uint4*)&Bt[(size_t)(tn * 128 + row) * 640 + kt * 64 + lkc];
      *(uint4*)&Bs[row][lkc] = vb;
    }
    __syncthreads();
#pragma unroll
    for (int kk = 0; kk < 64; kk += 32) {
      f16x8 af[4], bf[4];
#pragma unroll
      for (int mt = 0; mt < 4; ++mt)
        af[mt] = *(const f16x8*)&As[wm * 64 + mt * 16 + (lane & 15)][kk + (lane >> 4) * 8];
#pragma unroll
      for (int nt = 0; nt < 4; ++nt)
        bf[nt] = *(const f16x8*)&Bs[wn * 64 + nt * 16 + (lane & 15)][kk + (lane >> 4) * 8];
#pragma unroll
      for (int mt = 0; mt < 4; ++mt)
#pragma unroll
        for (int nt = 0; nt < 4; ++nt)
          acc[mt][nt] = __builtin_amdgcn_mfma_f32_16x16x32_f16(af[mt], bf[nt], acc[mt][nt], 0, 0, 0);
    }
    __syncthreads();
  }

  const int crow0 = tm * 128 + wm * 64 + (lane >> 4) * 4;
  const int ccol0 = tn * 128 + wn * 64 + (lane & 15);
#pragma unroll
  for (int mt = 0; mt < 4; ++mt)
#pragma unroll
    for (int q = 0; q < 4; ++q) {
      int grow = crow0 + mt * 16 + q;
      if (grow < Mrows) {
#pragma unroll
        for (int nt = 0; nt < 4; ++nt)
          C[(size_t)grow * 512 + ccol0 + nt * 16] = acc[mt][nt][q];
      }
    }
}

// ---------------------------------------------------------------------------
// pipe_step v4 (power-diet): grid = 28 blocks only.
//   blk 0..11  : rec layer=blk>>2, group=blk&3  (R13-verified body + gfr2)
//   blk 12..19 : gemm1 — 8 WGs, each 4 Mtiles (tm = (g>>1)+4*i, tn = g&1)
//   blk 20..27 : gemm2 — same decomposition
// Active CUs: 28 (was 76) -> lower package power, higher boost clock.
// Stream order carries all cross-stage deps; no spins/fences/atomics.
// ---------------------------------------------------------------------------
__global__ __launch_bounds__(512, 2) void pipe_step(
    float* __restrict__ out0, float* __restrict__ out1, float* __restrict__ out2,
    const _Float16* __restrict__ whT16, const _Float16* __restrict__ wiT16,
    int ca, int cb, int cc, int cd, int ce) {
  __shared__ char ldsRaw[163840];
  const int blk = blockIdx.x;
  const int tid = threadIdx.x;
  const int lane = tid & 63, wid = tid >> 6;
  const int nL[3] = {511, 509, 505};

  if (blk < 12) {
    // ------------------------------ REC role ------------------------------
    const int l = blk >> 2;
    const int gg = blk & 3;
    const int chunk = (l == 0) ? ca : (l == 1) ? cb : cc;
    if (chunk < 0 || chunk >= NCH) return;
    const int n = nL[l];
    const int s0 = chunk * CHS;
    if (s0 >= n) return;
    const int ns = (s0 + CHS < n) ? CHS : (n - s0);
    float* po = (l == 0) ? out0 : (l == 1) ? out1 : out2;
    const _Float16* whT = whT16 + (size_t)l * 262144;

    _Float16* hstage = (_Float16*)ldsRaw;            // 2 x 8192 f16 = 32 KB
    _Float16* Blds = (_Float16*)(ldsRaw + 32768);    // 128 KB, kb 10..13

    const int colbase = wid * 64;
    const int bq = lane & 15;
    const int u = lane >> 4;
    const int gnb = wid * 4;

    // Blds fill (kb 10..13, frag order)
    {
      uint4* B4 = (uint4*)Blds;
      for (int p = 0; p < 16; ++p) {
        int flat = p * 512 + tid;
        int ll = flat & 63;
        int gn = (flat >> 6) & 31;
        int kbl = flat >> 11;
        B4[flat] = *(const uint4*)&whT[(size_t)(gn * 16 + (ll & 15)) * 512 +
                                       (kbl + 10) * 32 + (ll >> 4) * 8];
      }
    }
    // kb 0..9 -> registers, residency forced (R8-verified)
    f16x8 bfr[4][10];
    {
#pragma unroll
      for (int nt = 0; nt < 4; ++nt) {
        const int j = colbase + nt * 16 + bq;
#pragma unroll
        for (int kb = 0; kb < 10; ++kb)
          bfr[nt][kb] = *(const f16x8*)&whT[(size_t)j * 512 + kb * 32 + u * 8];
      }
#pragma unroll
      for (int nt = 0; nt < 4; ++nt)
#pragma unroll
        for (int kb = 0; kb < 10; ++kb) asm volatile("" : "+v"(bfr[nt][kb]));
    }
    // chunk-start: re-stage h_{s0-1} from f32 out into hstage slot map
    if (s0 > 0) {
      _Float16* hw0 = hstage + ((s0 - 1) & 1) * 8192;
      for (int rep = 0; rep < 2; ++rep) {
        int idx = rep * 512 + tid;          // 0..1023
        int lb = idx >> 6;                  // 0..15
        int j0 = (idx & 63) * 8;
        const float* s = po + (size_t)(s0 - 1) * 32768 + (size_t)(gg * 16 + lb) * 512 + j0;
        float4 x0 = *(const float4*)s;
        float4 x1 = *(const float4*)(s + 4);
        f16x8 hv;
        hv[0] = (_Float16)x0.x; hv[1] = (_Float16)x0.y;
        hv[2] = (_Float16)x0.z; hv[3] = (_Float16)x0.w;
        hv[4] = (_Float16)x1.x; hv[5] = (_Float16)x1.y;
        hv[6] = (_Float16)x1.z; hv[7] = (_Float16)x1.w;
        int slot2 = (j0 >> 5) * 64 + ((j0 >> 3) & 3) * 16 + (lb ^ ((j0 >> 3) & 1));
        *(f16x8*)&hw0[slot2 * 8] = hv;
      }
    }
    __syncthreads();

    const int b0g = gg * 16;
    const size_t base = (size_t)(b0g + bq) * 512 + colbase + u * 4;

#define AFRD(kb) (*(const f16x8*)&hs[((kb)*64 + u * 16 + (bq ^ (u & 1))) * 8])
#define BLRD(kb, nt) \
  (*(const f16x8*)&Blds[((((kb)-10) * 32 + gnb + (nt)) * 64 + lane) * 8])
#define GLOAD(kb, nt) \
  (*(const f16x8*)&whT[(size_t)(colbase + (nt)*16 + bq) * 512 + (kb)*32 + u * 8])

    for (int t = s0; t < s0 + ns; ++t) {
      const float* pc = po + (size_t)t * 32768 + base;
      f32x4 pre[4];
#pragma unroll
      for (int nt = 0; nt < 4; ++nt) pre[nt] = *(const f32x4*)&pc[nt * 16];

      f32x4 acc[4] = {};
      if (t > 0) {
        const _Float16* hs = hstage + ((t - 1) & 1) * 8192;
        constexpr int seq[16] = {10, 0, 1, 2, 3, 11, 4, 5, 14, 12, 6, 7, 13, 8, 9, 15};
        constexpr int lnx[16] = {11, -1, -1, -1, -1, 12, -1, -1, -1, 13, -1, -1, -1, -1, -1, -1};
        // gfr2: BOTH streamed k-blocks issued up-front (full MFMA-phase cover)
        f16x8 g14[4], g15[4];
#pragma unroll
        for (int nt = 0; nt < 4; ++nt) g14[nt] = GLOAD(14, nt);
#pragma unroll
        for (int nt = 0; nt < 4; ++nt) g15[nt] = GLOAD(15, nt);
        f16x8 afr[4];
#pragma unroll
        for (int i = 0; i < 4; ++i) afr[i] = AFRD(seq[i]);
        f16x8 blr[4];
#pragma unroll
        for (int nt = 0; nt < 4; ++nt) blr[nt] = BLRD(10, nt);

#pragma unroll
        for (int i = 0; i < 16; ++i) {
          const int kb = seq[i];
          f16x8 a = afr[i & 3];
          if (i + 4 < 16) afr[i & 3] = AFRD(seq[i + 4]);
          if (kb < 10) {
#pragma unroll
            for (int nt = 0; nt < 4; ++nt)
              acc[nt] = __builtin_amdgcn_mfma_f32_16x16x32_f16(bfr[nt][kb], a, acc[nt], 0, 0, 0);
          } else if (kb < 14) {
            f16x8 w[4];
#pragma unroll
            for (int nt = 0; nt < 4; ++nt) w[nt] = blr[nt];
            if (lnx[i] >= 0) {
#pragma unroll
              for (int nt = 0; nt < 4; ++nt) blr[nt] = BLRD(lnx[i], nt);
            }
#pragma unroll
            for (int nt = 0; nt < 4; ++nt)
              acc[nt] = __builtin_amdgcn_mfma_f32_16x16x32_f16(w[nt], a, acc[nt], 0, 0, 0);
          } else if (kb == 14) {
#pragma unroll
            for (int nt = 0; nt < 4; ++nt)
              acc[nt] = __builtin_amdgcn_mfma_f32_16x16x32_f16(g14[nt], a, acc[nt], 0, 0, 0);
          } else {
#pragma unroll
            for (int nt = 0; nt < 4; ++nt)
              acc[nt] = __builtin_amdgcn_mfma_f32_16x16x32_f16(g15[nt], a, acc[nt], 0, 0, 0);
          }
        }
      }

      _Float16* hw = hstage + (t & 1) * 8192;
      float* pw = po + (size_t)t * 32768 + base;
#pragma unroll
      for (int nt = 0; nt < 4; ++nt) {
        const int J = colbase + nt * 16 + u * 4;
        const int slot2 = (J >> 5) * 64 + ((J >> 3) & 3) * 16 + (bq ^ ((J >> 3) & 1));
        f16x4 h4;
#pragma unroll
        for (int q = 0; q < 4; ++q) {
          float a = acc[nt][q] + pre[nt][q];
          float e = __builtin_amdgcn_exp2f(a * 2.8853900817779268f);
          float h = 1.f - 2.f * __builtin_amdgcn_rcpf(e + 1.f);
          acc[nt][q] = h;
          h4[q] = (_Float16)h;
        }
        *(f16x4*)&hw[slot2 * 8 + (J & 7)] = h4;
        *(f32x4*)&pw[nt * 16] = acc[nt];
      }
      asm volatile("s_waitcnt lgkmcnt(0)\n\ts_barrier" ::: "memory");
    }
#undef AFRD
#undef BLRD
#undef GLOAD
  } else {
    // ------------------------------ GEMM role ------------------------------
    // out_l[t][b][:] += h_{l-1}[t+toff][b][:] @ wi_l   (C-add; launch-ordered)
    // 8 WGs per gemm; each covers 4 Mtiles (tn fixed).
    const int gi = blk - 12;            // 0..15
    const int which = gi >> 3;          // 0: gemm1, 1: gemm2
    const int g = gi & 7;               // 0..7
    const int chunk = which ? ce : cd;
    if (chunk < 0 || chunk >= NCH) return;
    const int l = which + 1;
    const int n = nL[l];
    const int t0 = chunk * CHS;
    if (t0 >= n) return;
    const int t1 = (t0 + CHS < n) ? (t0 + CHS) : n;
    const int Mrows = (t1 - t0) * 64;
    const int Mbase = t0 * 64;
    const int toff = which ? 3 : 1;
    const float* hsrc = which ? out1 : out0;
    float* C = which ? out2 : out1;
    const _Float16* Bt = wiT16 + (size_t)which * 262144;  // [n=512][k=512]

    const int tn = g & 1;               // 0..1  (2 Ntiles of 256 cols)
    _Float16(*As)[72] = (_Float16(*)[72])ldsRaw;                    // 128x72
    _Float16(*Bs)[72] = (_Float16(*)[72])(ldsRaw + 128 * 72 * 2);   // 256x72
    const int wm = wid >> 2, wn = wid & 3;

    for (int pass = 0; pass < 4; ++pass) {
      const int tm = (g >> 1) + pass * 4;   // covers 0..15 across 4 WGs x 4
      if (tm * 128 >= Mrows) break;
      f32x4 acc[4][4] = {};

      for (int kt = 0; kt < 8; ++kt) {
        // A: 128 rows x 64 k (f32 source -> f16), 1024 8-f16 pieces, 2/thread
        for (int rep = 0; rep < 2; ++rep) {
          int idx = rep * 512 + tid;
          int row = idx >> 3;
          int kc8 = (idx & 7) * 8;
          f16x8 hv = {};
          if (tm * 128 + row < Mrows) {
            int grow = Mbase + tm * 128 + row;
            int tt = grow >> 6, bb = grow & 63;
            const float* s = hsrc + (size_t)(tt + toff) * 32768 + (size_t)bb * 512 + kt * 64 + kc8;
            float4 x0 = *(const float4*)s;
            float4 x1 = *(const float4*)(s + 4);
            hv[0] = (_Float16)x0.x; hv[1] = (_Float16)x0.y;
            hv[2] = (_Float16)x0.z; hv[3] = (_Float16)x0.w;
            hv[4] = (_Float16)x1.x; hv[5] = (_Float16)x1.y;
            hv[6] = (_Float16)x1.z; hv[7] = (_Float16)x1.w;
          }
          *(f16x8*)&As[row][kc8] = hv;
        }
        // B: 256 rows x 64 k f16, 2048 pieces, 4/thread
        for (int rep = 0; rep < 4; ++rep) {
          int idx = rep * 512 + tid;
          int row = idx >> 3;
          int kc8 = (idx & 7) * 8;
          *(uint4*)&Bs[row][kc8] =
              *(const uint4*)&Bt[(size_t)(tn * 256 + row) * 512 + kt * 64 + kc8];
        }
        __syncthreads();
#pragma unroll
        for (int kk = 0; kk < 64; kk += 32) {
          f16x8 af[4], bf[4];
#pragma unroll
          for (int mt = 0; mt < 4; ++mt)
            af[mt] = *(const f16x8*)&As[wm * 64 + mt * 16 + (lane & 15)][kk + (lane >> 4) * 8];
#pragma unroll
          for (int nt = 0; nt < 4; ++nt)
            bf[nt] = *(const f16x8*)&Bs[wn * 64 + nt * 16 + (lane & 15)][kk + (lane >> 4) * 8];
#pragma unroll
          for (int mt = 0; mt < 4; ++mt)
#pragma unroll
            for (int nt = 0; nt < 4; ++nt)
              acc[mt][nt] = __builtin_amdgcn_mfma_f32_16x16x32_f16(af[mt], bf[nt], acc[mt][nt], 0, 0, 0);
        }
        __syncthreads();
      }

      const int crow0 = tm * 128 + wm * 64 + (lane >> 4) * 4;
      const int ccol0 = tn * 256 + wn * 64 + (lane & 15);
#pragma unroll
      for (int mt = 0; mt < 4; ++mt)
#pragma unroll
        for (int q = 0; q < 4; ++q) {
          int lrow = crow0 + mt * 16 + q;
          if (lrow < Mrows) {
            size_t grow = (size_t)(Mbase + lrow);
#pragma unroll
            for (int nt = 0; nt < 4; ++nt)
              C[grow * 512 + ccol0 + nt * 16] += acc[mt][nt][q];
          }
        }
      __syncthreads();
    }
  }
}

// ---------------------------------------------------------------------------
extern "C" void kernel_launch(void* const* d_in, const int* in_sizes, int n_in,
                              void* d_out, int out_size, void* d_ws, size_t ws_size,
                              hipStream_t stream) {
  const float* inputs = (const float*)d_in[0];
  const float* wi[3] = {(const float*)d_in[1], (const float*)d_in[4], (const float*)d_in[7]};
  const float* wsm[3] = {(const float*)d_in[2], (const float*)d_in[5], (const float*)d_in[8]};
  const float* wh[3] = {(const float*)d_in[3], (const float*)d_in[6], (const float*)d_in[9]};
  float* out = (float*)d_out;

  char* wsp = (char*)d_ws;
  _Float16* whT16 = (_Float16*)wsp;                   // 1,572,864
  _Float16* wiT16 = (_Float16*)(wsp + 1572864);       // 1,048,576
  _Float16* wcat = (_Float16*)(wsp + 2621440);        // 1,966,080
  _Float16* Abuf = (_Float16*)(wsp + 4587520);        // prologue only

  for (int l = 0; l < 3; ++l)
    prepT<<<1024, 256, 0, stream>>>(whT16 + (size_t)l * 262144, wh[l]);
  prepT<<<1024, 256, 0, stream>>>(wiT16, wi[1]);
  prepT<<<1024, 256, 0, stream>>>(wiT16 + 262144, wi[2]);
  prep_wcat2<<<1024, 256, 0, stream>>>(wcat, wi[0], wsm[0], wsm[1], wsm[2]);

  const int nL[3] = {511, 509, 505};
  const long offL[3] = {0L, 511L * 32768, (511L + 509L) * 32768};
  float* out0 = out;
  float* out1 = out + offL[1];
  float* out2 = out + offL[2];

  // prologue: layer0 full pre; layer1/2 preS (ws terms)
  build_A<<<4096, 256, 0, stream>>>(Abuf, inputs, nullptr, nL[0], 128, 1, 0);
  gemm_f16<<<dim3(4, (nL[0] * 64 + 127) / 128), 256, 0, stream>>>(
      Abuf, wcat, out0, nL[0] * 64, 256);
  build_A<<<2048, 256, 0, stream>>>(Abuf, inputs, nullptr, nL[1], 0, 2, 1);
  gemm_f16<<<dim3(4, (nL[1] * 64 + 127) / 128), 256, 0, stream>>>(
      Abuf, wcat + 512 * 640, out1, nL[1] * 64, 128);
  build_A<<<2048, 256, 0, stream>>>(Abuf, inputs, nullptr, nL[2], 0, 4, 1);
  gemm_f16<<<dim3(4, (nL[2] * 64 + 127) / 128), 256, 0, stream>>>(
      Abuf, wcat + 2 * 512 * 640, out2, nL[2] * 64, 128);

  // chunked pipeline: launch i runs rec0[i] | gemm1[i-2] | rec1[i-3]
  //                   | gemm2[i-5] | rec2[i-6]; stream order = dependencies.
  for (int i = 0; i <= NCH + 5; ++i)
    pipe_step<<<28, 512, 0, stream>>>(out0, out1, out2, whT16, wiT16,
                                      i, i - 3, i - 6, i - 2, i - 5);
}

// Round 17
// 2915.452 us; speedup vs baseline: 1.1934x; 1.0223x over previous
//
#include <hip/hip_runtime.h>

#define T_DIM 512
#define B_DIM 64
#define F_DIM 128
#define H_DIM 512
#define CHS 32   // chunk steps
#define NCH 16   // chunks per layer

typedef _Float16 f16x8 __attribute__((ext_vector_type(8)));
typedef _Float16 f16x4 __attribute__((ext_vector_type(4)));
typedef float f32x4 __attribute__((ext_vector_type(4)));

// ---------------------------------------------------------------------------
// prep: dst[j][k] f16 = src[k][j]
// ---------------------------------------------------------------------------
__global__ void prepT(_Float16* __restrict__ dst, const float* __restrict__ src) {
  int idx = blockIdx.x * blockDim.x + threadIdx.x;
  if (idx < 262144) {
    int j = idx >> 9, k = idx & 511;
    dst[idx] = (_Float16)src[k * 512 + j];
  }
}

// ---------------------------------------------------------------------------
// prep: wcat[l][n=512][kc=640]: l0 [wi0|ws0]; l1 ws1; l2 ws2
// ---------------------------------------------------------------------------
__global__ void prep_wcat2(_Float16* __restrict__ dst, const float* __restrict__ wi0,
                           const float* __restrict__ ws0, const float* __restrict__ ws1,
                           const float* __restrict__ ws2) {
  const long total = 3L * 512 * 640;
  for (long idx = (long)blockIdx.x * blockDim.x + threadIdx.x; idx < total;
       idx += (long)gridDim.x * blockDim.x) {
    int l = (int)(idx / 327680);
    int rem = (int)(idx % 327680);
    int n = rem / 640, kc = rem % 640;
    float v = 0.f;
    if (l == 0) {
      if (kc < 128) v = wi0[kc * 512 + n];
      else if (kc < 256) v = ws0[(kc - 128) * 512 + n];
    } else {
      const float* ws = (l == 1) ? ws1 : ws2;
      if (kc < 128) v = ws[kc * 512 + n];
    }
    dst[idx] = (_Float16)v;
  }
}

// ---------------------------------------------------------------------------
// build A' panel f16 (verified; inK=0 -> sxs-only width-128 panel)
// ---------------------------------------------------------------------------
__global__ void build_A(_Float16* __restrict__ Abuf, const float* __restrict__ xin,
                        const float* __restrict__ prev, int n, int inK, int scale,
                        int layer) {
  const int Kcat = inK + 128;
  const long total = (long)n * 64 * Kcat;
  for (long idx = (long)blockIdx.x * blockDim.x + threadIdx.x; idx < total;
       idx += (long)gridDim.x * blockDim.x) {
    int k = (int)(idx % Kcat);
    long r = idx / Kcat;
    int b = (int)(r & 63);
    int t = (int)(r >> 6);
    float v;
    if (k < inK) {
      if (layer == 0) v = xin[((long)b * T_DIM + t) * F_DIM + k];
      else v = prev[((long)(t + scale - 1) * B_DIM + b) * H_DIM + k];
    } else {
      int kk = k - inK;
      int t0 = t + scale - 1;
      float s = 0.f;
      for (int w = 0; w < scale; ++w) s += xin[((long)b * T_DIM + t0 + w) * F_DIM + kk];
      v = s * (1.f / scale);
    }
    Abuf[idx] = (_Float16)v;
  }
}

// ---------------------------------------------------------------------------
// f16 MFMA GEMM (prologue, verified; B stride 640)
// ---------------------------------------------------------------------------
__global__ __launch_bounds__(256) void gemm_f16(const _Float16* __restrict__ A,
                                                const _Float16* __restrict__ Bt,
                                                float* __restrict__ C, int Mrows,
                                                int Kcat) {
  __shared__ _Float16 As[128][72];
  __shared__ _Float16 Bs[128][72];
  const int tid = threadIdx.x;
  const int tn = blockIdx.x, tm = blockIdx.y;
  const int lane = tid & 63, wid = tid >> 6;
  const int wm = wid >> 1, wn = wid & 1;
  f32x4 acc[4][4] = {};
  const int nK = Kcat >> 6;
  const int lrow = tid >> 3, lkc = (tid & 7) * 8;

  for (int kt = 0; kt < nK; ++kt) {
    for (int r = 0; r < 4; ++r) {
      int row = r * 32 + lrow;
      int grow = tm * 128 + row;
      uint4 va = make_uint4(0u, 0u, 0u, 0u);
      if (grow < Mrows) va = *(const uint4*)&A[(size_t)grow * Kcat + kt * 64 + lkc];
      *(uint4*)&As[row][lkc] = va;
      uint4 vb = *(const uint4*)&Bt[(size_t)(tn * 128 + row) * 640 + kt * 64 + lkc];
      *(uint4*)&Bs[row][lkc] = vb;
    }
    __syncthreads();
#pragma unroll
    for (int kk = 0; kk < 64; kk += 32) {
      f16x8 af[4], bf[4];
#pragma unroll
      for (int mt = 0; mt < 4; ++mt)
        af[mt] = *(const f16x8*)&As[wm * 64 + mt * 16 + (lane & 15)][kk + (lane >> 4) * 8];
#pragma unroll
      for (int nt = 0; nt < 4; ++nt)
        bf[nt] = *(const f16x8*)&Bs[wn * 64 + nt * 16 + (lane & 15)][kk + (lane >> 4) * 8];
#pragma unroll
      for (int mt = 0; mt < 4; ++mt)
#pragma unroll
        for (int nt = 0; nt < 4; ++nt)
          acc[mt][nt] = __builtin_amdgcn_mfma_f32_16x16x32_f16(af[mt], bf[nt], acc[mt][nt], 0, 0, 0);
    }
    __syncthreads();
  }

  const int crow0 = tm * 128 + wm * 64 + (lane >> 4) * 4;
  const int ccol0 = tn * 128 + wn * 64 + (lane & 15);
#pragma unroll
  for (int mt = 0; mt < 4; ++mt)
#pragma unroll
    for (int q = 0; q < 4; ++q) {
      int grow = crow0 + mt * 16 + q;
      if (grow < Mrows) {
#pragma unroll
        for (int nt = 0; nt < 4; ++nt)
          C[(size_t)grow * 512 + ccol0 + nt * 16] = acc[mt][nt][q];
      }
    }
}

// ---------------------------------------------------------------------------
// pipe_step (R13, best measured): 76 blocks of 512 threads:
//   [0..3]   rec0 chunk ca (group = blk&3)
//   [4..7]   rec1 chunk cb
//   [8..11]  rec2 chunk cc
//   [12..43] gemm1 chunk cd (out1 += h0[t+1] @ wi1)   32 WGs: 16 Mtiles x 2 Ntiles
//   [44..75] gemm2 chunk ce (out2 += h1[t+3] @ wi2)
// All cross-stage deps are satisfied by PREVIOUS launches (stream order);
// no spins / fences / atomics. rec body = verified R8 loop; chunk-start h
// re-staged from the layer's f32 out slice.
// ---------------------------------------------------------------------------
__global__ __launch_bounds__(512, 2) void pipe_step(
    float* __restrict__ out0, float* __restrict__ out1, float* __restrict__ out2,
    const _Float16* __restrict__ whT16, const _Float16* __restrict__ wiT16,
    int ca, int cb, int cc, int cd, int ce) {
  __shared__ char ldsRaw[163840];
  const int blk = blockIdx.x;
  const int tid = threadIdx.x;
  const int lane = tid & 63, wid = tid >> 6;
  const int nL[3] = {511, 509, 505};

  if (blk < 12) {
    // ------------------------------ REC role ------------------------------
    const int l = blk >> 2;
    const int gg = blk & 3;
    const int chunk = (l == 0) ? ca : (l == 1) ? cb : cc;
    if (chunk < 0 || chunk >= NCH) return;
    const int n = nL[l];
    const int s0 = chunk * CHS;
    if (s0 >= n) return;
    const int ns = (s0 + CHS < n) ? CHS : (n - s0);
    float* po = (l == 0) ? out0 : (l == 1) ? out1 : out2;
    const _Float16* whT = whT16 + (size_t)l * 262144;

    _Float16* hstage = (_Float16*)ldsRaw;            // 2 x 8192 f16 = 32 KB
    _Float16* Blds = (_Float16*)(ldsRaw + 32768);    // 128 KB, kb 10..13

    const int colbase = wid * 64;
    const int bq = lane & 15;
    const int u = lane >> 4;
    const int gnb = wid * 4;

    // Blds fill (kb 10..13, frag order)
    {
      uint4* B4 = (uint4*)Blds;
      for (int p = 0; p < 16; ++p) {
        int flat = p * 512 + tid;
        int ll = flat & 63;
        int gn = (flat >> 6) & 31;
        int kbl = flat >> 11;
        B4[flat] = *(const uint4*)&whT[(size_t)(gn * 16 + (ll & 15)) * 512 +
                                       (kbl + 10) * 32 + (ll >> 4) * 8];
      }
    }
    // kb 0..9 -> registers, residency forced (R8-verified)
    f16x8 bfr[4][10];
    {
#pragma unroll
      for (int nt = 0; nt < 4; ++nt) {
        const int j = colbase + nt * 16 + bq;
#pragma unroll
        for (int kb = 0; kb < 10; ++kb)
          bfr[nt][kb] = *(const f16x8*)&whT[(size_t)j * 512 + kb * 32 + u * 8];
      }
#pragma unroll
      for (int nt = 0; nt < 4; ++nt)
#pragma unroll
        for (int kb = 0; kb < 10; ++kb) asm volatile("" : "+v"(bfr[nt][kb]));
    }
    // chunk-start: re-stage h_{s0-1} from f32 out into hstage slot map
    if (s0 > 0) {
      _Float16* hw0 = hstage + ((s0 - 1) & 1) * 8192;
      for (int rep = 0; rep < 2; ++rep) {
        int idx = rep * 512 + tid;          // 0..1023
        int lb = idx >> 6;                  // 0..15
        int j0 = (idx & 63) * 8;
        const float* s = po + (size_t)(s0 - 1) * 32768 + (size_t)(gg * 16 + lb) * 512 + j0;
        float4 x0 = *(const float4*)s;
        float4 x1 = *(const float4*)(s + 4);
        f16x8 hv;
        hv[0] = (_Float16)x0.x; hv[1] = (_Float16)x0.y;
        hv[2] = (_Float16)x0.z; hv[3] = (_Float16)x0.w;
        hv[4] = (_Float16)x1.x; hv[5] = (_Float16)x1.y;
        hv[6] = (_Float16)x1.z; hv[7] = (_Float16)x1.w;
        int slot = (j0 >> 5) * 64 + ((j0 >> 3) & 3) * 16 + (lb ^ ((j0 >> 3) & 1));
        *(f16x8*)&hw0[slot * 8] = hv;
      }
    }
    __syncthreads();

    const int b0g = gg * 16;
    const size_t base = (size_t)(b0g + bq) * 512 + colbase + u * 4;

#define AFRD(kb) (*(const f16x8*)&hs[((kb)*64 + u * 16 + (bq ^ (u & 1))) * 8])
#define BLRD(kb, nt) \
  (*(const f16x8*)&Blds[((((kb)-10) * 32 + gnb + (nt)) * 64 + lane) * 8])
#define GLOAD(kb, nt) \
  (*(const f16x8*)&whT[(size_t)(colbase + (nt)*16 + bq) * 512 + (kb)*32 + u * 8])

    for (int t = s0; t < s0 + ns; ++t) {
      const float* pc = po + (size_t)t * 32768 + base;
      f32x4 pre[4];
#pragma unroll
      for (int nt = 0; nt < 4; ++nt) pre[nt] = *(const f32x4*)&pc[nt * 16];

      f32x4 acc[4] = {};
      if (t > 0) {
        const _Float16* hs = hstage + ((t - 1) & 1) * 8192;
        constexpr int seq[16] = {10, 0, 1, 2, 3, 11, 4, 5, 14, 12, 6, 7, 13, 8, 9, 15};
        constexpr int lnx[16] = {11, -1, -1, -1, -1, 12, -1, -1, -1, 13, -1, -1, -1, -1, -1, -1};
        f16x8 afr[4];
#pragma unroll
        for (int i = 0; i < 4; ++i) afr[i] = AFRD(seq[i]);
        f16x8 blr[4];
#pragma unroll
        for (int nt = 0; nt < 4; ++nt) blr[nt] = BLRD(10, nt);
        f16x8 gfr[4];
#pragma unroll
        for (int nt = 0; nt < 4; ++nt) gfr[nt] = GLOAD(14, nt);

#pragma unroll
        for (int i = 0; i < 16; ++i) {
          const int kb = seq[i];
          f16x8 a = afr[i & 3];
          if (i + 4 < 16) afr[i & 3] = AFRD(seq[i + 4]);
          if (kb < 10) {
#pragma unroll
            for (int nt = 0; nt < 4; ++nt)
              acc[nt] = __builtin_amdgcn_mfma_f32_16x16x32_f16(bfr[nt][kb], a, acc[nt], 0, 0, 0);
          } else if (kb < 14) {
            f16x8 w[4];
#pragma unroll
            for (int nt = 0; nt < 4; ++nt) w[nt] = blr[nt];
            if (lnx[i] >= 0) {
#pragma unroll
              for (int nt = 0; nt < 4; ++nt) blr[nt] = BLRD(lnx[i], nt);
            }
#pragma unroll
            for (int nt = 0; nt < 4; ++nt)
              acc[nt] = __builtin_amdgcn_mfma_f32_16x16x32_f16(w[nt], a, acc[nt], 0, 0, 0);
          } else if (kb == 14) {
            f16x8 w[4];
#pragma unroll
            for (int nt = 0; nt < 4; ++nt) w[nt] = gfr[nt];
#pragma unroll
            for (int nt = 0; nt < 4; ++nt) gfr[nt] = GLOAD(15, nt);
#pragma unroll
            for (int nt = 0; nt < 4; ++nt)
              acc[nt] = __builtin_amdgcn_mfma_f32_16x16x32_f16(w[nt], a, acc[nt], 0, 0, 0);
          } else {
#pragma unroll
            for (int nt = 0; nt < 4; ++nt)
              acc[nt] = __builtin_amdgcn_mfma_f32_16x16x32_f16(gfr[nt], a, acc[nt], 0, 0, 0);
          }
        }
      }

      _Float16* hw = hstage + (t & 1) * 8192;
      float* pw = po + (size_t)t * 32768 + base;
#pragma unroll
      for (int nt = 0; nt < 4; ++nt) {
        const int J = colbase + nt * 16 + u * 4;
        const int slot = (J >> 5) * 64 + ((J >> 3) & 3) * 16 + (bq ^ ((J >> 3) & 1));
        f16x4 h4;
#pragma unroll
        for (int q = 0; q < 4; ++q) {
          float a = acc[nt][q] + pre[nt][q];
          float e = __builtin_amdgcn_exp2f(a * 2.8853900817779268f);
          float h = 1.f - 2.f * __builtin_amdgcn_rcpf(e + 1.f);
          acc[nt][q] = h;
          h4[q] = (_Float16)h;
        }
        *(f16x4*)&hw[slot * 8 + (J & 7)] = h4;
        *(f32x4*)&pw[nt * 16] = acc[nt];
      }
      asm volatile("s_waitcnt lgkmcnt(0)\n\ts_barrier" ::: "memory");
    }
#undef AFRD
#undef BLRD
#undef GLOAD
  } else {
    // ------------------------------ GEMM role ------------------------------
    // out_l[t][b][:] += h_{l-1}[t+toff][b][:] @ wi_l   (C-add; launch-ordered)
    const int gi = blk - 12;
    const int which = gi >> 5;  // 0: gemm1, 1: gemm2
    const int g = gi & 31;
    const int chunk = which ? ce : cd;
    if (chunk < 0 || chunk >= NCH) return;
    const int l = which + 1;
    const int n = nL[l];
    const int t0 = chunk * CHS;
    if (t0 >= n) return;
    const int t1 = (t0 + CHS < n) ? (t0 + CHS) : n;
    const int Mrows = (t1 - t0) * 64;
    const int Mbase = t0 * 64;
    const int toff = which ? 3 : 1;
    const float* hsrc = which ? out1 : out0;
    float* C = which ? out2 : out1;
    const _Float16* Bt = wiT16 + (size_t)which * 262144;  // [n=512][k=512]

    const int tm = g >> 1, tn = g & 1;  // 16 Mtiles x 2 Ntiles (BM=128, BN=256)
    _Float16(*As)[72] = (_Float16(*)[72])ldsRaw;                    // 128x72
    _Float16(*Bs)[72] = (_Float16(*)[72])(ldsRaw + 128 * 72 * 2);   // 256x72
    const int wm = wid >> 2, wn = wid & 3;
    f32x4 acc[4][4] = {};

    for (int kt = 0; kt < 8; ++kt) {
      // A: 128 rows x 64 k (f32 source -> f16), 1024 8-f16 pieces, 2/thread
      for (int rep = 0; rep < 2; ++rep) {
        int idx = rep * 512 + tid;
        int row = idx >> 3;
        int kc8 = (idx & 7) * 8;
        f16x8 hv = {};
        if (tm * 128 + row < Mrows) {
          int grow = Mbase + tm * 128 + row;
          int tt = grow >> 6, bb = grow & 63;
          const float* s = hsrc + (size_t)(tt + toff) * 32768 + (size_t)bb * 512 + kt * 64 + kc8;
          float4 x0 = *(const float4*)s;
          float4 x1 = *(const float4*)(s + 4);
          hv[0] = (_Float16)x0.x; hv[1] = (_Float16)x0.y;
          hv[2] = (_Float16)x0.z; hv[3] = (_Float16)x0.w;
          hv[4] = (_Float16)x1.x; hv[5] = (_Float16)x1.y;
          hv[6] = (_Float16)x1.z; hv[7] = (_Float16)x1.w;
        }
        *(f16x8*)&As[row][kc8] = hv;
      }
      // B: 256 rows x 64 k f16, 2048 pieces, 4/thread
      for (int rep = 0; rep < 4; ++rep) {
        int idx = rep * 512 + tid;
        int row = idx >> 3;
        int kc8 = (idx & 7) * 8;
        *(uint4*)&Bs[row][kc8] =
            *(const uint4*)&Bt[(size_t)(tn * 256 + row) * 512 + kt * 64 + kc8];
      }
      __syncthreads();
#pragma unroll
      for (int kk = 0; kk < 64; kk += 32) {
        f16x8 af[4], bf[4];
#pragma unroll
        for (int mt = 0; mt < 4; ++mt)
          af[mt] = *(const f16x8*)&As[wm * 64 + mt * 16 + (lane & 15)][kk + (lane >> 4) * 8];
#pragma unroll
        for (int nt = 0; nt < 4; ++nt)
          bf[nt] = *(const f16x8*)&Bs[wn * 64 + nt * 16 + (lane & 15)][kk + (lane >> 4) * 8];
#pragma unroll
        for (int mt = 0; mt < 4; ++mt)
#pragma unroll
          for (int nt = 0; nt < 4; ++nt)
            acc[mt][nt] = __builtin_amdgcn_mfma_f32_16x16x32_f16(af[mt], bf[nt], acc[mt][nt], 0, 0, 0);
      }
      __syncthreads();
    }

    const int crow0 = tm * 128 + wm * 64 + (lane >> 4) * 4;
    const int ccol0 = tn * 256 + wn * 64 + (lane & 15);
#pragma unroll
    for (int mt = 0; mt < 4; ++mt)
#pragma unroll
      for (int q = 0; q < 4; ++q) {
        int lrow = crow0 + mt * 16 + q;
        if (lrow < Mrows) {
          size_t grow = (size_t)(Mbase + lrow);
#pragma unroll
          for (int nt = 0; nt < 4; ++nt)
            C[grow * 512 + ccol0 + nt * 16] += acc[mt][nt][q];
        }
      }
  }
}

// ---------------------------------------------------------------------------
extern "C" void kernel_launch(void* const* d_in, const int* in_sizes, int n_in,
                              void* d_out, int out_size, void* d_ws, size_t ws_size,
                              hipStream_t stream) {
  const float* inputs = (const float*)d_in[0];
  const float* wi[3] = {(const float*)d_in[1], (const float*)d_in[4], (const float*)d_in[7]};
  const float* wsm[3] = {(const float*)d_in[2], (const float*)d_in[5], (const float*)d_in[8]};
  const float* wh[3] = {(const float*)d_in[3], (const float*)d_in[6], (const float*)d_in[9]};
  float* out = (float*)d_out;

  char* wsp = (char*)d_ws;
  _Float16* whT16 = (_Float16*)wsp;                   // 1,572,864
  _Float16* wiT16 = (_Float16*)(wsp + 1572864);       // 1,048,576
  _Float16* wcat = (_Float16*)(wsp + 2621440);        // 1,966,080
  _Float16* Abuf = (_Float16*)(wsp + 4587520);        // prologue only

  for (int l = 0; l < 3; ++l)
    prepT<<<1024, 256, 0, stream>>>(whT16 + (size_t)l * 262144, wh[l]);
  prepT<<<1024, 256, 0, stream>>>(wiT16, wi[1]);
  prepT<<<1024, 256, 0, stream>>>(wiT16 + 262144, wi[2]);
  prep_wcat2<<<1024, 256, 0, stream>>>(wcat, wi[0], wsm[0], wsm[1], wsm[2]);

  const int nL[3] = {511, 509, 505};
  const long offL[3] = {0L, 511L * 32768, (511L + 509L) * 32768};
  float* out0 = out;
  float* out1 = out + offL[1];
  float* out2 = out + offL[2];

  // prologue: layer0 full pre; layer1/2 preS (ws terms)
  build_A<<<4096, 256, 0, stream>>>(Abuf, inputs, nullptr, nL[0], 128, 1, 0);
  gemm_f16<<<dim3(4, (nL[0] * 64 + 127) / 128), 256, 0, stream>>>(
      Abuf, wcat, out0, nL[0] * 64, 256);
  build_A<<<2048, 256, 0, stream>>>(Abuf, inputs, nullptr, nL[1], 0, 2, 1);
  gemm_f16<<<dim3(4, (nL[1] * 64 + 127) / 128), 256, 0, stream>>>(
      Abuf, wcat + 512 * 640, out1, nL[1] * 64, 128);
  build_A<<<2048, 256, 0, stream>>>(Abuf, inputs, nullptr, nL[2], 0, 4, 1);
  gemm_f16<<<dim3(4, (nL[2] * 64 + 127) / 128), 256, 0, stream>>>(
      Abuf, wcat + 2 * 512 * 640, out2, nL[2] * 64, 128);

  // chunked pipeline: launch i runs rec0[i] | gemm1[i-2] | rec1[i-3]
  //                   | gemm2[i-5] | rec2[i-6]; stream order = dependencies.
  for (int i = 0; i <= NCH + 5; ++i)
    pipe_step<<<76, 512, 0, stream>>>(out0, out1, out2, whT16, wiT16,
                                      i, i - 3, i - 6, i - 2, i - 5);
}